// Round 12
// baseline (759.467 us; speedup 1.0000x reference)
//
#include <hip/hip_runtime.h>

// BERT encoder block fwd. R12: persistent-block GEMM, R5-redux with 3 fixes:
//  (1) boundary vmcnt(4) BEFORE epilogue (only prefetch loads outstanding),
//  (2) epilogue staged in the free 32KB (buf1.h1 regions; next tile's K0->buf0,
//      K1.h0->buf1.h0 with NT even) in 4 batches of 64 rows,
//  (3) raw s_barrier in epilogue (NO __syncthreads: it drains vmcnt and would
//      kill the cross-tile prefetch -- the hidden R5 failure mode).
// K-loop schedule, swizzles, MODEs identical to R11. prep/LN/VTt unchanged.

typedef __attribute__((ext_vector_type(4))) float  f32x4;
typedef __attribute__((ext_vector_type(8))) short  s16x8;
typedef __attribute__((ext_vector_type(4))) short  s16x4;
typedef unsigned short u16;
typedef unsigned int   u32;

__device__ __forceinline__ float bf2f(short s) {
  u32 u = ((u32)(u16)s) << 16;
  float f; __builtin_memcpy(&f, &u, 4); return f;
}
__device__ __forceinline__ short f2bf(float f) {
  u32 u; __builtin_memcpy(&u, &f, 4);
  u32 r = (u + 0x7fffu + ((u >> 16) & 1u)) >> 16;   // RNE
  return (short)(u16)r;
}

__device__ __forceinline__ void gload16(const void* g, void* l) {
  __builtin_amdgcn_global_load_lds(
      (const __attribute__((address_space(1))) u32*)g,
      (__attribute__((address_space(3))) u32*)l, 16, 0, 0);
}

// stage one 128-row half of a 256x64 bf16 tile (2 gload16/thread, 512 threads)
__device__ __forceinline__ void stage_half(const char* gop, long long ldb,
                                           long long rowbase, int tt, int h,
                                           u16* ldsop, int tid) {
#pragma unroll
  for (int l = 0; l < 2; ++l) {
    const int o   = (l * 512 + tid) * 16;
    const int rih = o >> 7;
    const int scb = (o & 127) ^ ((rih & 7) << 4);
    gload16(gop + (rowbase + h * 128 + rih) * ldb + (long long)tt * 128 + scb,
            (char*)ldsop + h * 16384 + o);
  }
}

#define SABUF(c) (SMEM + (c) * 16384)
#define SBBUF(c) (SMEM + 32768 + (c) * 16384)
// epilogue pieces: buf1 h1 halves (free while next tile's K0/K1.h0 are staged)
#define EP0 (SMEM + 24576)   /* SABUF(1)+8192: 16KB = 32 rows x 512B */
#define EP1 (SMEM + 57344)   /* SBBUF(1)+8192: 16KB */

#define RD_A(MH) do { _Pragma("unroll") for (int mi = 0; mi < 4; ++mi) { \
    const int row_ = wm * 64 + (MH) * 128 + mi * 16 + lr; \
    const int sw_ = (row_ & 7) << 4; const int rb_ = row_ << 7; \
    _Pragma("unroll") for (int kk = 0; kk < 2; ++kk) \
      af[mi][kk] = *(const s16x8*)(pa + rb_ + (((kk << 6) | (kg << 4)) ^ sw_)); } } while (0)

#define RD_B(NH) do { _Pragma("unroll") for (int nj = 0; nj < 2; ++nj) { \
    const int row_ = wn * 32 + (NH) * 128 + nj * 16 + lr; \
    const int sw_ = (row_ & 7) << 4; const int rb_ = row_ << 7; \
    _Pragma("unroll") for (int kk = 0; kk < 2; ++kk) \
      bf[NH][nj][kk] = *(const s16x8*)(pb + rb_ + (((kk << 6) | (kg << 4)) ^ sw_)); } } while (0)

#define MM(MH, NH) do { _Pragma("unroll") for (int kk = 0; kk < 2; ++kk) \
    _Pragma("unroll") for (int mi = 0; mi < 4; ++mi) \
    _Pragma("unroll") for (int nj = 0; nj < 2; ++nj) \
      acc[(MH) * 4 + mi][(NH) * 2 + nj] = __builtin_amdgcn_mfma_f32_16x16x32_bf16( \
        af[mi][kk], bf[NH][nj][kk], acc[(MH) * 4 + mi][(NH) * 2 + nj], 0, 0, 0); } while (0)

#define PH_SYNC do { __builtin_amdgcn_s_barrier(); \
    asm volatile("s_waitcnt lgkmcnt(0)"); \
    __builtin_amdgcn_sched_barrier(0); } while (0)

// bijective XCD permutation over ntiles (ntiles % 8 == 0 for all our calls)
__device__ __forceinline__ int perm8(int orig, int ntiles) {
  const int q = ntiles >> 3, r8 = ntiles & 7;
  const int xcd = orig & 7, pos = orig >> 3;
  return (xcd < r8 ? xcd * (q + 1) : r8 * (q + 1) + (xcd - r8) * q) + pos;
}

// MODE: 1=+bias; 2=relu(+bias); 3=exp(scale*acc)+rowsum atomics; 4=acc/lsum;
//       5=+bias, route col>>10 to three [*,1024] outputs spaced 16777216 (QKV).
template<int MODE>
__global__ __launch_bounds__(512, 2)
void gemm256p(const u16* __restrict__ A, const u16* __restrict__ BT,
              u16* __restrict__ C,
              const float* __restrict__ bias0, const float* __restrict__ bias1,
              const float* __restrict__ bias2, float* __restrict__ lsum,
              int M, int N, int K, int NBZ,
              long long sA, long long sB, long long sC, float scale) {
  __shared__ u16 SMEM[65536];

  const int tn = N >> 8;
  const int tilesPerZ = (M >> 8) * tn;
  const int ntiles = NBZ * tilesPerZ;
  const int NT = K >> 6;                   // even for all our K (16/32/64)
  const long long ldb = (long long)K * 2;
  const int G = gridDim.x;

  const int tid = threadIdx.x;
  const int lane = tid & 63, wid = tid >> 6;
  const int lr = lane & 15, kg = lane >> 4;
  const int wm = wid >> 2, wn = wid & 3;

  const char *curA, *curB, *nxtA, *nxtB;
  long long curBm, curBn, nxtBm, nxtBn;
  int curZ, nxtZ;
  auto mk = [&](int tl, const char*& ag, const char*& bg,
                long long& bm, long long& bn, int& z) {
    z = tl / tilesPerZ;
    const int rm = tl - z * tilesPerZ;
    bm = (long long)(rm / tn) << 8;
    bn = (long long)(rm - (rm / tn) * tn) << 8;
    ag = (const char*)(A + (long long)z * sA);
    bg = (const char*)(BT + (long long)z * sB);
  };

  int jt = blockIdx.x;
  mk(perm8(jt, ntiles), curA, curB, curBm, curBn, curZ);
  bool hasNext = (jt + G) < ntiles;
  if (hasNext) mk(perm8(jt + G, ntiles), nxtA, nxtB, nxtBm, nxtBn, nxtZ);
  else { nxtA = curA; nxtB = curB; nxtBm = curBm; nxtBn = curBn; nxtZ = curZ; }

  f32x4 acc[8][4] = {};
  s16x8 af[4][2];
  s16x8 bf[2][2][2];

  // prologue (once per block): K0 fully + K1 h0-halves
  stage_half(curA, ldb, curBm, 0, 0, SABUF(0), tid);
  stage_half(curB, ldb, curBn, 0, 0, SBBUF(0), tid);
  stage_half(curA, ldb, curBm, 0, 1, SABUF(0), tid);
  stage_half(curB, ldb, curBn, 0, 1, SBBUF(0), tid);
  stage_half(curA, ldb, curBm, 1, 0, SABUF(1), tid);
  stage_half(curB, ldb, curBn, 1, 0, SBBUF(1), tid);
  asm volatile("s_waitcnt vmcnt(4)");
  __builtin_amdgcn_s_barrier();

  for (;;) {
    for (int T = 0; T < NT; ++T) {
      const int c = T & 1, cn = c ^ 1;   // == vt&1 since NT even
      const char* pa = (const char*)SABUF(c);
      const char* pb = (const char*)SBBUF(c);

      const bool in1 = (T + 1 < NT), in2 = (T + 2 < NT);
      const bool v1 = in1 || hasNext, v2 = in2 || hasNext;
      const char* a1 = in1 ? curA : nxtA;  const char* b1 = in1 ? curB : nxtB;
      const long long m1 = in1 ? curBm : nxtBm, n1 = in1 ? curBn : nxtBn;
      const int tk1 = in1 ? T + 1 : 0;
      const char* a2 = in2 ? curA : nxtA;  const char* b2 = in2 ? curB : nxtB;
      const long long m2 = in2 ? curBm : nxtBm, n2 = in2 ? curBn : nxtBn;
      const int tk2 = in2 ? T + 2 : T + 2 - NT;

      // phase 0: (mh0,nh0); stage (vt+1).Ah1 -> buf cn
      RD_A(0); RD_B(0);
      if (v1) stage_half(a1, ldb, m1, tk1, 1, SABUF(cn), tid);
      PH_SYNC;
      __builtin_amdgcn_s_setprio(1); MM(0, 0); __builtin_amdgcn_s_setprio(0);
      __builtin_amdgcn_s_barrier();

      // phase 1: (mh0,nh1); stage (vt+1).Bh1 -> buf cn
      RD_B(1);
      if (v1) stage_half(b1, ldb, n1, tk1, 1, SBBUF(cn), tid);
      PH_SYNC;
      __builtin_amdgcn_s_setprio(1); MM(0, 1); __builtin_amdgcn_s_setprio(0);
      __builtin_amdgcn_s_barrier();

      // phase 2: (mh1,nh0); stage (vt+2).Ah0 -> buf c
      RD_A(1);
      if (v2) stage_half(a2, ldb, m2, tk2, 0, SABUF(c), tid);
      PH_SYNC;
      __builtin_amdgcn_s_setprio(1); MM(1, 0); __builtin_amdgcn_s_setprio(0);
      __builtin_amdgcn_s_barrier();

      // phase 3: (mh1,nh1); stage (vt+2).Bh0 -> buf c; counted boundary wait
      if (v2) stage_half(b2, ldb, n2, tk2, 0, SBBUF(c), tid);
      PH_SYNC;
      __builtin_amdgcn_s_setprio(1); MM(1, 1); __builtin_amdgcn_s_setprio(0);
      if (v2)      { asm volatile("s_waitcnt vmcnt(4)"); }
      else if (v1) { asm volatile("s_waitcnt vmcnt(0)"); }
      __builtin_amdgcn_s_barrier();
    }

    // ---- epilogue for cur: 4 batches of 64 rows through EP0/EP1 (32KB free).
    // Raw barriers only; prefetched loads for next tile stay in flight.
    {
      u16* Cb = C + (long long)curZ * sC;
      const long long zM = (long long)curZ * M;
      u16* obase; long long ldc, bnl;
      const float* bptr = bias0;
      if (MODE == 5) {
        const int sel = (int)(curBn >> 10);
        obase = C + (long long)sel * 16777216;
        ldc = 1024; bnl = curBn & 1023;
        bptr = (sel == 0 ? bias0 : sel == 1 ? bias1 : bias2);
      } else { obase = Cb; ldc = N; bnl = curBn; }

      float bvv[2][2];
      if (MODE == 1 || MODE == 2 || MODE == 5) {
#pragma unroll
        for (int nh = 0; nh < 2; ++nh)
#pragma unroll
          for (int nj = 0; nj < 2; ++nj)
            bvv[nh][nj] = bptr[bnl + wn * 32 + nh * 128 + nj * 16 + lr];
      }

#pragma unroll
      for (int b = 0; b < 4; ++b) {
        const int mh = b >> 1;
        if (wm == (b & 1)) {
#pragma unroll
          for (int nh = 0; nh < 2; ++nh)
#pragma unroll
            for (int nj = 0; nj < 2; ++nj) {
              const int col = wn * 32 + nh * 128 + nj * 16 + lr;
#pragma unroll
              for (int mi = 0; mi < 4; ++mi)
#pragma unroll
                for (int r = 0; r < 4; ++r) {
                  const int lrow = mi * 16 + kg * 4 + r;   // 0..63 in batch
                  float v = acc[mh * 4 + mi][nh * 2 + nj][r];
                  if (MODE == 1 || MODE == 2 || MODE == 5) v = v * scale + bvv[nh][nj];
                  if (MODE == 2) v = fmaxf(v, 0.f);
                  if (MODE == 3) v = __expf(v * scale);
                  if (MODE == 4) v = v / lsum[zM + curBm + b * 64 + lrow];
                  u16* ep = (lrow < 32) ? EP0 : EP1;
                  ep[(lrow & 31) * 256 + (col ^ (kg << 4))] = (u16)f2bf(v);
                }
            }
        }
        asm volatile("s_waitcnt lgkmcnt(0)" ::: "memory");
        __builtin_amdgcn_sched_barrier(0);
        __builtin_amdgcn_s_barrier();
#pragma unroll
        for (int i = 0; i < 4; ++i) {
          const int o    = (i * 512 + tid) * 16;       // byte offset in 32KB batch
          const int lrow = o >> 9;                     // 0..63
          const int wb   = o & 511;
          const int gs   = (wb >> 4) ^ (((lrow >> 2) & 3) << 1);
          const u16* ep  = (lrow < 32) ? EP0 : EP1;
          s16x8 d = *(const s16x8*)((const char*)ep + (lrow & 31) * 512 + (gs << 4));
          if (MODE == 3) {
            float s = 0.f;
#pragma unroll
            for (int j = 0; j < 8; ++j) s += bf2f(d[j]);
#pragma unroll
            for (int off = 1; off < 32; off <<= 1) s += __shfl_xor(s, off);
            if ((lane & 31) == 0) atomicAdd(&lsum[zM + curBm + b * 64 + lrow], s);
          }
          *(s16x8*)((char*)obase + (((long long)curBm + b * 64 + lrow) * ldc + bnl) * 2 + wb) = d;
        }
        __builtin_amdgcn_s_barrier();   // all reads done before region reuse
      }
    }

    jt += G;
    if (jt >= ntiles) break;
    curA = nxtA; curB = nxtB; curBm = nxtBm; curBn = nxtBn; curZ = nxtZ;
    hasNext = (jt + G) < ntiles;
    if (hasNext) mk(perm8(jt + G, ntiles), nxtA, nxtB, nxtBm, nxtBn, nxtZ);
#pragma unroll
    for (int i = 0; i < 8; ++i)
#pragma unroll
      for (int j = 0; j < 4; ++j) acc[i][j] = (f32x4){0.f, 0.f, 0.f, 0.f};
  }
}

// ------------------------------------------- prep: cast x->bf16 + 6 weight transposes
__global__ __launch_bounds__(256) void prep(
    const float* __restrict__ x,  u16* __restrict__ XB,
    const float* __restrict__ Wq, const float* __restrict__ Wk,
    const float* __restrict__ Wv, const float* __restrict__ Wo,
    const float* __restrict__ W1, const float* __restrict__ W2,
    u16* __restrict__ WQT, u16* __restrict__ WKT, u16* __restrict__ WVT,
    u16* __restrict__ WOT, u16* __restrict__ W1T, u16* __restrict__ W2T) {
  __shared__ float tile[32][33];
  const int bid = blockIdx.x;
  const int t = threadIdx.x;
  if (bid < 16384) {
    const long long i = (long long)bid * 256 + t;
    f32x4 v = ((const f32x4*)x)[i];
    s16x4 o;
#pragma unroll
    for (int j = 0; j < 4; j++) o[j] = f2bf(v[j]);
    ((s16x4*)XB)[i] = o;
    return;
  }
  const float* in; u16* out; int R, C, tb;
  if (bid < 20480) {
    const int w = (bid - 16384) >> 10;
    tb = (bid - 16384) & 1023;
    in  = (w == 0 ? Wq : w == 1 ? Wk : w == 2 ? Wv : Wo);
    out = (w == 0 ? WQT : w == 1 ? WKT : w == 2 ? WVT : WOT);
    R = 1024; C = 1024;
  } else if (bid < 24576) {
    tb = bid - 20480; in = W1; out = W1T; R = 1024; C = 4096;
  } else {
    tb = bid - 24576; in = W2; out = W2T; R = 4096; C = 1024;
  }
  const int tpr = C >> 5;
  const int r0 = (tb / tpr) * 32, c0 = (tb % tpr) * 32;
  const int tx = t & 31, ty = t >> 5;
#pragma unroll
  for (int i = 0; i < 32; i += 8)
    tile[ty + i][tx] = in[(long long)(r0 + ty + i) * C + (c0 + tx)];
  __syncthreads();
#pragma unroll
  for (int i = 0; i < 32; i += 8)
    out[(long long)(c0 + ty + i) * R + (r0 + tx)] = (u16)f2bf(tile[tx][ty + i]);
}

// ------------------------------------------------- transpose bf16 (batched)
__global__ __launch_bounds__(256) void transpose_bf16_bf16(const u16* __restrict__ in,
                                                           u16* __restrict__ out,
                                                           int R, int C,
                                                           long long isb, long long osb) {
  __shared__ u16 tile[32][33];
  in  += (long long)blockIdx.z * isb;
  out += (long long)blockIdx.z * osb;
  const int tx = threadIdx.x, ty = threadIdx.y;
  const int r0 = blockIdx.y * 32, c0 = blockIdx.x * 32;
#pragma unroll
  for (int i = 0; i < 32; i += 8)
    tile[ty + i][tx] = in[(long long)(r0 + ty + i) * C + (c0 + tx)];
  __syncthreads();
#pragma unroll
  for (int i = 0; i < 32; i += 8)
    out[(long long)(c0 + ty + i) * R + (r0 + tx)] = tile[tx][ty + i];
}

// ------------------------------------------- LN(a_bf16 + b_bf16) -> bf16 or f32
template<bool OUTF32>
__global__ __launch_bounds__(256) void ln_add(const u16* __restrict__ a,
                                              const u16* __restrict__ b,
                                              const float* __restrict__ g,
                                              const float* __restrict__ be,
                                              void* __restrict__ outp) {
  const long long row = blockIdx.x;
  const int t = threadIdx.x;
  s16x4 avv = ((const s16x4*)(a + row * 1024))[t];
  s16x4 bvv = ((const s16x4*)(b + row * 1024))[t];
  float v[4]; float sum = 0.f, ss = 0.f;
#pragma unroll
  for (int j = 0; j < 4; j++) { v[j] = bf2f(avv[j]) + bf2f(bvv[j]); sum += v[j]; ss += v[j] * v[j]; }
#pragma unroll
  for (int off = 32; off > 0; off >>= 1) { sum += __shfl_xor(sum, off); ss += __shfl_xor(ss, off); }
  __shared__ float red[8];
  if ((t & 63) == 0) { red[t >> 6] = sum; red[4 + (t >> 6)] = ss; }
  __syncthreads();
  sum = (red[0] + red[1]) + (red[2] + red[3]);
  ss  = (red[4] + red[5]) + (red[6] + red[7]);
  const float mu   = sum * (1.f / 1024.f);
  const float var  = ss * (1.f / 1024.f) - mu * mu;
  const float rstd = rsqrtf(var + 1e-5f);
  if (OUTF32) {
    f32x4 o;
#pragma unroll
    for (int j = 0; j < 4; j++) {
      const int c = t * 4 + j;
      o[j] = (v[j] - mu) * rstd * g[c] + be[c];
    }
    ((f32x4*)((float*)outp + row * 1024))[t] = o;
  } else {
    s16x4 o;
#pragma unroll
    for (int j = 0; j < 4; j++) {
      const int c = t * 4 + j;
      o[j] = f2bf((v[j] - mu) * rstd * g[c] + be[c]);
    }
    *(s16x4*)&((u16*)outp)[row * 1024 + t * 4] = o;
  }
}

// ---------------------------------------------------------------- launcher
extern "C" void kernel_launch(void* const* d_in, const int* in_sizes, int n_in,
                              void* d_out, int out_size, void* d_ws, size_t ws_size,
                              hipStream_t stream) {
  const float* x   = (const float*)d_in[0];
  const float* Wq  = (const float*)d_in[1];
  const float* bq  = (const float*)d_in[2];
  const float* Wk  = (const float*)d_in[3];
  const float* bk  = (const float*)d_in[4];
  const float* Wv  = (const float*)d_in[5];
  const float* bv  = (const float*)d_in[6];
  const float* Wo  = (const float*)d_in[7];
  const float* bo  = (const float*)d_in[8];
  const float* g1  = (const float*)d_in[9];
  const float* b1  = (const float*)d_in[10];
  const float* g2  = (const float*)d_in[11];
  const float* b2  = (const float*)d_in[12];
  const float* W1  = (const float*)d_in[13];
  const float* bf1 = (const float*)d_in[14];
  const float* W2  = (const float*)d_in[15];
  const float* bf2 = (const float*)d_in[16];
  float* out = (float*)d_out;

  // ws layout identical to R11 (liveness-checked):
  char* ws = (char*)d_ws;
  u16* wsWQT = (u16*)(ws + 0);
  u16* wsWKT = (u16*)(ws + 2097152);
  u16* wsWVT = (u16*)(ws + 4194304);
  u16* wsWOT = (u16*)(ws + 6291456);
  u16* wsW1T = (u16*)(ws + 8388608);
  u16* wsW2T = (u16*)(ws + 16777216);
  u16* wsXB  = (u16*)(ws + 25165824);
  u16* wsQ   = (u16*)(ws + 58720256);
  u16* wsK   = (u16*)(ws + 92274688);
  u16* wsV   = (u16*)(ws + 125829120);
  u16* wsVT  = (u16*)(ws + 159383552);
  u16* wsS   = (u16*)(ws + 192937984);
  u16* wsAO  = wsQ;
  u16* wsAO2 = wsS;
  u16* wsH   = (u16*)(ws + 192937984 + 33554432);
  u16* wsHID = wsXB;
  u16* wsFFN = wsS;
  float* wsLSUM = (float*)wsV;

  const dim3 tb(32, 8, 1);
  const float inv_sqrt_e = 0.03125f;
  const float* nf = nullptr;
  float* nfm = nullptr;

  // 1) prep: cast + all weight transposes
  prep<<<28672, 256, 0, stream>>>(x, wsXB, Wq, Wk, Wv, Wo, W1, W2,
                                  wsWQT, wsWKT, wsWVT, wsWOT, wsW1T, wsW2T);

  // 2) fused QKV: 768 tiles, 3/block
  gemm256p<5><<<256, 512, 0, stream>>>(wsXB, wsWQT, wsQ, bq, bk, bv, nfm,
                                       16384, 3072, 1024, 1, 0, 0, 0, 1.f);

  // 3) V -> V^T per batch; zero lsum (V now dead)
  transpose_bf16_bf16<<<dim3(32, 64, 8), tb, 0, stream>>>(wsV, wsVT, 2048, 1024, 2048LL * 1024, 1024LL * 2048);
  hipMemsetAsync(wsLSUM, 0, 16384 * sizeof(float), stream);

  // 4) P~ = exp(QK^T/32) + rowsum atomics: 512 tiles, 2/block
  gemm256p<3><<<256, 512, 0, stream>>>(wsQ, wsK, wsS, nf, nf, nf, wsLSUM,
                                       2048, 2048, 1024, 8,
                                       2048LL * 1024, 2048LL * 1024, 2048LL * 2048, inv_sqrt_e);

  // 5) attn_out = (P~ V)/l : 256 tiles
  gemm256p<4><<<256, 512, 0, stream>>>(wsS, wsVT, wsAO, nf, nf, nf, wsLSUM,
                                       2048, 1024, 2048, 8,
                                       2048LL * 2048, 1024LL * 2048, 2048LL * 1024, 1.f);

  // 6) out-proj: 256 tiles
  gemm256p<1><<<256, 512, 0, stream>>>(wsAO, wsWOT, wsAO2, bo, nf, nf, nfm,
                                       16384, 1024, 1024, 1, 0, 0, 0, 1.f);

  // 7) h = LN(XB + AO2)
  ln_add<false><<<16384, 256, 0, stream>>>(wsXB, wsAO2, g1, b1, wsH);

  // 8) HID = relu(h W1 + bf1): 1024 tiles, 4/block
  gemm256p<2><<<256, 512, 0, stream>>>(wsH, wsW1T, wsHID, bf1, nf, nf, nfm,
                                       16384, 4096, 1024, 1, 0, 0, 0, 1.f);

  // 9) FFN = HID W2 + bf2: 256 tiles
  gemm256p<1><<<256, 512, 0, stream>>>(wsHID, wsW2T, wsFFN, bf2, nf, nf, nfm,
                                       16384, 1024, 4096, 1, 0, 0, 0, 1.f);

  // 10) out = LN(H + FFN), fp32
  ln_add<true><<<16384, 256, 0, stream>>>(wsH, wsFFN, g2, b2, out);

  (void)in_sizes; (void)n_in; (void)out_size; (void)ws_size;
}

// Round 13
// 603.804 us; speedup vs baseline: 1.2578x; 1.2578x over previous
//
#include <hip/hip_runtime.h>

// BERT encoder block fwd. R13 = R11 core (verbatim revert from R12's failed
// persistence) + V^T computed directly as a GEMM: VT = Wv^T X^T via the same
// kernel (A=WVT, BT=XB per batch, MODE 6 = bias-by-row). Deletes the V buffer
// and the 64MB V->VT transpose round-trip. QKV shrinks to QK (N=2048, 2-way
// routing). lsum lives in the freed V region.

typedef __attribute__((ext_vector_type(4))) float  f32x4;
typedef __attribute__((ext_vector_type(8))) short  s16x8;
typedef __attribute__((ext_vector_type(4))) short  s16x4;
typedef unsigned short u16;
typedef unsigned int   u32;

__device__ __forceinline__ float bf2f(short s) {
  u32 u = ((u32)(u16)s) << 16;
  float f; __builtin_memcpy(&f, &u, 4); return f;
}
__device__ __forceinline__ short f2bf(float f) {
  u32 u; __builtin_memcpy(&u, &f, 4);
  u32 r = (u + 0x7fffu + ((u >> 16) & 1u)) >> 16;   // RNE
  return (short)(u16)r;
}

__device__ __forceinline__ void gload16(const void* g, void* l) {
  __builtin_amdgcn_global_load_lds(
      (const __attribute__((address_space(1))) u32*)g,
      (__attribute__((address_space(3))) u32*)l, 16, 0, 0);
}

// stage one 128-row half of a 256x64 bf16 tile (2 gload16/thread, 512 threads)
__device__ __forceinline__ void stage_half(const char* gop, long long ldb,
                                           long long rowbase, int tt, int h,
                                           u16* ldsop, int tid) {
#pragma unroll
  for (int l = 0; l < 2; ++l) {
    const int o   = (l * 512 + tid) * 16;          // linear byte offset in half (16 KiB)
    const int rih = o >> 7;                        // row in half 0..127
    const int scb = (o & 127) ^ ((rih & 7) << 4);  // inverse-swizzled source col-byte
    gload16(gop + (rowbase + h * 128 + rih) * ldb + (long long)tt * 128 + scb,
            (char*)ldsop + h * 16384 + o);
  }
}

#define SABUF(c) (SMEM + (c) * 16384)
#define SBBUF(c) (SMEM + 32768 + (c) * 16384)

#define RD_A(MH) do { _Pragma("unroll") for (int mi = 0; mi < 4; ++mi) { \
    const int row_ = wm * 64 + (MH) * 128 + mi * 16 + lr; \
    const int sw_ = (row_ & 7) << 4; const int rb_ = row_ << 7; \
    _Pragma("unroll") for (int kk = 0; kk < 2; ++kk) \
      af[mi][kk] = *(const s16x8*)(pa + rb_ + (((kk << 6) | (kg << 4)) ^ sw_)); } } while (0)

#define RD_B(NH) do { _Pragma("unroll") for (int nj = 0; nj < 2; ++nj) { \
    const int row_ = wn * 32 + (NH) * 128 + nj * 16 + lr; \
    const int sw_ = (row_ & 7) << 4; const int rb_ = row_ << 7; \
    _Pragma("unroll") for (int kk = 0; kk < 2; ++kk) \
      bf[NH][nj][kk] = *(const s16x8*)(pb + rb_ + (((kk << 6) | (kg << 4)) ^ sw_)); } } while (0)

#define MM(MH, NH) do { _Pragma("unroll") for (int kk = 0; kk < 2; ++kk) \
    _Pragma("unroll") for (int mi = 0; mi < 4; ++mi) \
    _Pragma("unroll") for (int nj = 0; nj < 2; ++nj) \
      acc[(MH) * 4 + mi][(NH) * 2 + nj] = __builtin_amdgcn_mfma_f32_16x16x32_bf16( \
        af[mi][kk], bf[NH][nj][kk], acc[(MH) * 4 + mi][(NH) * 2 + nj], 0, 0, 0); } while (0)

#define PH_SYNC do { __builtin_amdgcn_s_barrier(); \
    asm volatile("s_waitcnt lgkmcnt(0)"); \
    __builtin_amdgcn_sched_barrier(0); } while (0)

// Epilogue MODE: 1 = +bias[col]; 2 = relu(+bias[col]); 3 = exp(scale*acc) +
//   row-sum atomics into lsum; 4 = acc / lsum[z*M+row]; 5 = +bias, route
//   col>>10 to two [*,1024] outputs spaced 16777216 elems (fused QK);
//   6 = +bias0[row] (V^T projection: rows are embedding dims).
template<int MODE>
__global__ __launch_bounds__(512, 2)
void gemm256(const u16* __restrict__ A, const u16* __restrict__ BT,
             u16* __restrict__ C,
             const float* __restrict__ bias0, const float* __restrict__ bias1,
             const float* __restrict__ bias2, float* __restrict__ lsum,
             int M, int N, int K, float scale,
             long long sA, long long sB, long long sC) {
  __shared__ u16 SMEM[65536];   // K-loop: SA dbuf | SB dbuf (4 x 16K u16); epilogue: [256][256]

  // T1: bijective XCD swizzle over flattened 3D grid (m204)
  const int gx = gridDim.x, gy = gridDim.y;
  const int nwg = gx * gy * gridDim.z;
  const int orig = (blockIdx.z * gy + blockIdx.y) * gx + blockIdx.x;
  const int q = nwg >> 3, r8 = nwg & 7;
  const int xcd = orig & 7, pos = orig >> 3;
  const int wg = (xcd < r8 ? xcd * (q + 1) : r8 * (q + 1) + (xcd - r8) * q) + pos;
  const int bz = wg / (gx * gy);
  const int rem = wg % (gx * gy);
  const long long bm = (long long)(rem / gx) * 256;
  const long long bn = (long long)(rem % gx) * 256;

  const char* Ag = (const char*)(A + (long long)bz * sA);
  const char* Bg = (const char*)(BT + (long long)bz * sB);
  u16* Cb = C + (long long)bz * sC;
  const long long ldb = (long long)K * 2;

  const int tid = threadIdx.x;
  const int lane = tid & 63, wid = tid >> 6;
  const int lr = lane & 15, kg = lane >> 4;
  const int wm = wid >> 2, wn = wid & 3;
  const int NT = K >> 6;

  f32x4 acc[8][4] = {};
  s16x8 af[4][2];
  s16x8 bf[2][2][2];

  // prologue: T0 fully + T1 first halves; wait T0 (4 loads may stay in flight)
  stage_half(Ag, ldb, bm, 0, 0, SABUF(0), tid);
  stage_half(Bg, ldb, bn, 0, 0, SBBUF(0), tid);
  stage_half(Ag, ldb, bm, 0, 1, SABUF(0), tid);
  stage_half(Bg, ldb, bn, 0, 1, SBBUF(0), tid);
  stage_half(Ag, ldb, bm, 1, 0, SABUF(1), tid);
  stage_half(Bg, ldb, bn, 1, 0, SBBUF(1), tid);
  asm volatile("s_waitcnt vmcnt(4)");
  __builtin_amdgcn_s_barrier();

  for (int T = 0; T < NT; ++T) {
    const int c = T & 1, cn = c ^ 1;
    const char* pa = (const char*)SABUF(c);
    const char* pb = (const char*)SBBUF(c);

    // ---- phase 0: quadrant (mh0, nh0); stage (T+1).Ah1
    RD_A(0); RD_B(0);
    if (T + 1 < NT) stage_half(Ag, ldb, bm, T + 1, 1, SABUF(cn), tid);
    PH_SYNC;
    __builtin_amdgcn_s_setprio(1); MM(0, 0); __builtin_amdgcn_s_setprio(0);
    __builtin_amdgcn_s_barrier();

    // ---- phase 1: (mh0, nh1); stage (T+1).Bh1
    RD_B(1);
    if (T + 1 < NT) stage_half(Bg, ldb, bn, T + 1, 1, SBBUF(cn), tid);
    PH_SYNC;
    __builtin_amdgcn_s_setprio(1); MM(0, 1); __builtin_amdgcn_s_setprio(0);
    __builtin_amdgcn_s_barrier();

    // ---- phase 2: (mh1, nh0); stage (T+2).Ah0
    RD_A(1);
    if (T + 2 < NT) stage_half(Ag, ldb, bm, T + 2, 0, SABUF(c), tid);
    PH_SYNC;
    __builtin_amdgcn_s_setprio(1); MM(1, 0); __builtin_amdgcn_s_setprio(0);
    __builtin_amdgcn_s_barrier();

    // ---- phase 3: (mh1, nh1); stage (T+2).Bh0; counted boundary wait
    if (T + 2 < NT) stage_half(Bg, ldb, bn, T + 2, 0, SBBUF(c), tid);
    PH_SYNC;
    __builtin_amdgcn_s_setprio(1); MM(1, 1); __builtin_amdgcn_s_setprio(0);
    if (T + 2 < NT)      { asm volatile("s_waitcnt vmcnt(4)"); }
    else if (T + 1 < NT) { asm volatile("s_waitcnt vmcnt(0)"); }
    __builtin_amdgcn_s_barrier();
  }

  // ---- epilogue: acc -> LDS (swizzled conflict-free) -> coalesced 16B stores.
  const long long zM = (long long)bz * M;
  u16* obase; long long ldc, bnl;
  const float* bptr = bias0;
  if (MODE == 5) {
    const int sel = (int)(bn >> 10);
    obase = C + (long long)sel * 16777216;
    ldc = 1024; bnl = bn & 1023;
    bptr = (sel == 0 ? bias0 : sel == 1 ? bias1 : bias2);
  } else { obase = Cb; ldc = N; bnl = bn; }

#pragma unroll
  for (int nh = 0; nh < 2; ++nh)
#pragma unroll
    for (int nj = 0; nj < 2; ++nj) {
      const int col = wn * 32 + nh * 128 + nj * 16 + lr;     // local col 0..255
      float bv = 0.f;
      if (MODE == 1 || MODE == 2 || MODE == 5) bv = bptr[bnl + col];
#pragma unroll
      for (int mh = 0; mh < 2; ++mh)
#pragma unroll
        for (int mi = 0; mi < 4; ++mi) {
          const int row0 = wm * 64 + mh * 128 + mi * 16 + kg * 4;  // local row
#pragma unroll
          for (int r = 0; r < 4; ++r) {
            float v = acc[mh * 4 + mi][nh * 2 + nj][r];
            if (MODE == 1 || MODE == 2 || MODE == 5) v = v * scale + bv;
            if (MODE == 2) v = fmaxf(v, 0.f);
            if (MODE == 3) v = __expf(v * scale);
            if (MODE == 4) v = v / lsum[zM + bm + row0 + r];
            if (MODE == 6) v = v * scale + bias0[bm + row0 + r];
            SMEM[(row0 + r) * 256 + (col ^ (kg << 4))] = (u16)f2bf(v);
          }
        }
    }
  __syncthreads();
#pragma unroll
  for (int i = 0; i < 16; ++i) {
    const int o   = (i * 512 + tid) * 16;          // byte offset in 128KiB tile
    const int row = o >> 9;                        // local row (512 B/row)
    const int wb  = o & 511;                       // byte-in-row = local col*2
    const int gs  = (wb >> 4) ^ (((row >> 2) & 3) << 1);  // inverse granule swizzle
    s16x8 d = *(const s16x8*)((const char*)SMEM + row * 512 + (gs << 4));
    if (MODE == 3) {
      float s = 0.f;
#pragma unroll
      for (int j = 0; j < 8; ++j) s += bf2f(d[j]);
#pragma unroll
      for (int off = 1; off < 32; off <<= 1) s += __shfl_xor(s, off);
      if ((lane & 31) == 0) atomicAdd(&lsum[zM + bm + row], s);
    }
    *(s16x8*)((char*)obase + (((long long)bm + row) * ldc + bnl) * 2 + wb) = d;
  }
}

// ------------------------------------------- prep: cast x->bf16 + 6 weight transposes
__global__ __launch_bounds__(256) void prep(
    const float* __restrict__ x,  u16* __restrict__ XB,
    const float* __restrict__ Wq, const float* __restrict__ Wk,
    const float* __restrict__ Wv, const float* __restrict__ Wo,
    const float* __restrict__ W1, const float* __restrict__ W2,
    u16* __restrict__ WQT, u16* __restrict__ WKT, u16* __restrict__ WVT,
    u16* __restrict__ WOT, u16* __restrict__ W1T, u16* __restrict__ W2T) {
  __shared__ float tile[32][33];
  const int bid = blockIdx.x;
  const int t = threadIdx.x;
  if (bid < 16384) {
    const long long i = (long long)bid * 256 + t;
    f32x4 v = ((const f32x4*)x)[i];
    s16x4 o;
#pragma unroll
    for (int j = 0; j < 4; j++) o[j] = f2bf(v[j]);
    ((s16x4*)XB)[i] = o;
    return;
  }
  const float* in; u16* out; int R, C, tb;
  if (bid < 20480) {
    const int w = (bid - 16384) >> 10;
    tb = (bid - 16384) & 1023;
    in  = (w == 0 ? Wq : w == 1 ? Wk : w == 2 ? Wv : Wo);
    out = (w == 0 ? WQT : w == 1 ? WKT : w == 2 ? WVT : WOT);
    R = 1024; C = 1024;
  } else if (bid < 24576) {
    tb = bid - 20480; in = W1; out = W1T; R = 1024; C = 4096;
  } else {
    tb = bid - 24576; in = W2; out = W2T; R = 4096; C = 1024;
  }
  const int tpr = C >> 5;
  const int r0 = (tb / tpr) * 32, c0 = (tb % tpr) * 32;
  const int tx = t & 31, ty = t >> 5;
#pragma unroll
  for (int i = 0; i < 32; i += 8)
    tile[ty + i][tx] = in[(long long)(r0 + ty + i) * C + (c0 + tx)];
  __syncthreads();
#pragma unroll
  for (int i = 0; i < 32; i += 8)
    out[(long long)(c0 + ty + i) * R + (r0 + tx)] = (u16)f2bf(tile[tx][ty + i]);
}

// ------------------------------------------- LN(a_bf16 + b_bf16) -> bf16 or f32
template<bool OUTF32>
__global__ __launch_bounds__(256) void ln_add(const u16* __restrict__ a,
                                              const u16* __restrict__ b,
                                              const float* __restrict__ g,
                                              const float* __restrict__ be,
                                              void* __restrict__ outp) {
  const long long row = blockIdx.x;
  const int t = threadIdx.x;
  s16x4 avv = ((const s16x4*)(a + row * 1024))[t];
  s16x4 bvv = ((const s16x4*)(b + row * 1024))[t];
  float v[4]; float sum = 0.f, ss = 0.f;
#pragma unroll
  for (int j = 0; j < 4; j++) { v[j] = bf2f(avv[j]) + bf2f(bvv[j]); sum += v[j]; ss += v[j] * v[j]; }
#pragma unroll
  for (int off = 32; off > 0; off >>= 1) { sum += __shfl_xor(sum, off); ss += __shfl_xor(ss, off); }
  __shared__ float red[8];
  if ((t & 63) == 0) { red[t >> 6] = sum; red[4 + (t >> 6)] = ss; }
  __syncthreads();
  sum = (red[0] + red[1]) + (red[2] + red[3]);
  ss  = (red[4] + red[5]) + (red[6] + red[7]);
  const float mu   = sum * (1.f / 1024.f);
  const float var  = ss * (1.f / 1024.f) - mu * mu;
  const float rstd = rsqrtf(var + 1e-5f);
  if (OUTF32) {
    f32x4 o;
#pragma unroll
    for (int j = 0; j < 4; j++) {
      const int c = t * 4 + j;
      o[j] = (v[j] - mu) * rstd * g[c] + be[c];
    }
    ((f32x4*)((float*)outp + row * 1024))[t] = o;
  } else {
    s16x4 o;
#pragma unroll
    for (int j = 0; j < 4; j++) {
      const int c = t * 4 + j;
      o[j] = f2bf((v[j] - mu) * rstd * g[c] + be[c]);
    }
    *(s16x4*)&((u16*)outp)[row * 1024 + t * 4] = o;
  }
}

// ---------------------------------------------------------------- launcher
extern "C" void kernel_launch(void* const* d_in, const int* in_sizes, int n_in,
                              void* d_out, int out_size, void* d_ws, size_t ws_size,
                              hipStream_t stream) {
  const float* x   = (const float*)d_in[0];
  const float* Wq  = (const float*)d_in[1];
  const float* bq  = (const float*)d_in[2];
  const float* Wk  = (const float*)d_in[3];
  const float* bk  = (const float*)d_in[4];
  const float* Wv  = (const float*)d_in[5];
  const float* bv  = (const float*)d_in[6];
  const float* Wo  = (const float*)d_in[7];
  const float* bo  = (const float*)d_in[8];
  const float* g1  = (const float*)d_in[9];
  const float* b1  = (const float*)d_in[10];
  const float* g2  = (const float*)d_in[11];
  const float* b2  = (const float*)d_in[12];
  const float* W1  = (const float*)d_in[13];
  const float* bf1 = (const float*)d_in[14];
  const float* W2  = (const float*)d_in[15];
  const float* bf2 = (const float*)d_in[16];
  float* out = (float*)d_out;

  // ws layout (bytes), liveness-checked aliasing:
  //  weights 0..25165824 (WQT/WKT contiguous for fused QK)
  //  XB  = 25165824  (32MiB)  cast -> LN1
  //  Q   = 58720256  (32MiB)  QK -> scores;   AO = Q after scores (PV -> Wo)
  //  K   = 92274688  (32MiB)  QK -> scores    (= Q + 16777216 elems, MODE5 sel 1)
  //  V   = 125829120 (32MiB)  FREE -> lsum at start (memset -> PV)
  //  VT  = 159383552 (32MiB)  VT-gemm -> PV
  //  S   = 192937984 (64MiB)  scores -> PV;   then AO2 = S+0 (Wo -> LN1),
  //                           H = S+32MiB (LN1 -> LN2), FFN = S+0 (FFN2 -> LN2)
  //  HID = XB..V end (128MiB) FFN1 -> FFN2 (XB/Q/K/V all dead by FFN1)
  char* ws = (char*)d_ws;
  u16* wsWQT = (u16*)(ws + 0);
  u16* wsWKT = (u16*)(ws + 2097152);
  u16* wsWVT = (u16*)(ws + 4194304);
  u16* wsWOT = (u16*)(ws + 6291456);
  u16* wsW1T = (u16*)(ws + 8388608);
  u16* wsW2T = (u16*)(ws + 16777216);
  u16* wsXB  = (u16*)(ws + 25165824);
  u16* wsQ   = (u16*)(ws + 58720256);
  u16* wsVT  = (u16*)(ws + 159383552);
  u16* wsS   = (u16*)(ws + 192937984);
  u16* wsAO  = wsQ;
  u16* wsAO2 = wsS;
  u16* wsH   = (u16*)(ws + 192937984 + 33554432);
  u16* wsHID = wsXB;
  u16* wsFFN = wsS;
  float* wsLSUM = (float*)(ws + 125829120);   // freed V region

  const float inv_sqrt_e = 0.03125f;   // 1/sqrt(1024)
  const float* nf = nullptr;
  float* nfm = nullptr;

  // 1) prep: cast x->bf16 + all weight transposes; zero lsum (independent)
  prep<<<28672, 256, 0, stream>>>(x, wsXB, Wq, Wk, Wv, Wo, W1, W2,
                                  wsWQT, wsWKT, wsWVT, wsWOT, wsW1T, wsW2T);
  hipMemsetAsync(wsLSUM, 0, 16384 * sizeof(float), stream);

  // 2) fused QK: [16384,1024] x [2048,1024]^T, routes col>>10 to Q / K (+bias)
  gemm256<5><<<dim3(8, 64, 1), 512, 0, stream>>>(wsXB, wsWQT, wsQ, bq, bk, nf, nfm,
                                                 16384, 2048, 1024, 1.f, 0, 0, 0);

  // 3) VT = Wv^T X^T per batch: A=WVT [1024,1024], BT=XB_z [2048,1024],
  //    C=VT_z [1024,2048], bias-by-row (MODE 6)
  gemm256<6><<<dim3(8, 4, 8), 512, 0, stream>>>(wsWVT, wsXB, wsVT, bv, nf, nf, nfm,
                                                1024, 2048, 1024, 1.f,
                                                0, 2048LL * 1024, 1024LL * 2048);

  // 4) P~ = exp(QK^T/32) + rowsum atomics into lsum
  gemm256<3><<<dim3(8, 8, 8), 512, 0, stream>>>(wsQ, (u16*)(ws + 92274688), wsS, nf, nf, nf, wsLSUM,
                                                2048, 2048, 1024, inv_sqrt_e,
                                                2048LL * 1024, 2048LL * 1024, 2048LL * 2048);

  // 5) attn_out = (P~ V)/l -> AO (=Q region; Q dead after scores)
  gemm256<4><<<dim3(4, 8, 8), 512, 0, stream>>>(wsS, wsVT, wsAO, nf, nf, nf, wsLSUM,
                                                2048, 1024, 2048, 1.f,
                                                2048LL * 2048, 1024LL * 2048, 2048LL * 1024);
  // 6) out-proj -> AO2 (=S region start; S dead after PV)
  gemm256<1><<<dim3(4, 64, 1), 512, 0, stream>>>(wsAO, wsWOT, wsAO2, bo, nf, nf, nfm,
                                                 16384, 1024, 1024, 1.f, 0, 0, 0);

  // 7) h = LN(XB + AO2) -> H (S + 32MiB)
  ln_add<false><<<16384, 256, 0, stream>>>(wsXB, wsAO2, g1, b1, wsH);

  // 8) HID = relu(h W1 + bf1) -> HID (=XB..V, 128MiB, all dead by now)
  gemm256<2><<<dim3(16, 64, 1), 512, 0, stream>>>(wsH, wsW1T, wsHID, bf1, nf, nf, nfm,
                                                  16384, 4096, 1024, 1.f, 0, 0, 0);

  // 9) FFN = HID W2 + bf2 -> FFN (=S start; AO2 dead after LN1)
  gemm256<1><<<dim3(4, 64, 1), 512, 0, stream>>>(wsHID, wsW2T, wsFFN, bf2, nf, nf, nfm,
                                                 16384, 1024, 4096, 1.f, 0, 0, 0);

  // 10) out = LN(H + FFN), fp32
  ln_add<true><<<16384, 256, 0, stream>>>(wsH, wsFFN, g2, b2, out);

  (void)in_sizes; (void)n_in; (void)out_size; (void)ws_size;
}

// Round 14
// 591.857 us; speedup vs baseline: 1.2832x; 1.0202x over previous
//
#include <hip/hip_runtime.h>

// BERT encoder block fwd. R14 = R13 + QK/VT merged into ONE dispatch (they are
// mutually independent; 768-block grid, XCD-swizzled jointly, routed wg<512 ->
// QK MODE5, else VT MODE6). GEMM core refactored into a __device__ body shared
// by the standalone wrapper and the merged kernel. Everything else R13 verbatim.

typedef __attribute__((ext_vector_type(4))) float  f32x4;
typedef __attribute__((ext_vector_type(8))) short  s16x8;
typedef __attribute__((ext_vector_type(4))) short  s16x4;
typedef unsigned short u16;
typedef unsigned int   u32;

__device__ __forceinline__ float bf2f(short s) {
  u32 u = ((u32)(u16)s) << 16;
  float f; __builtin_memcpy(&f, &u, 4); return f;
}
__device__ __forceinline__ short f2bf(float f) {
  u32 u; __builtin_memcpy(&u, &f, 4);
  u32 r = (u + 0x7fffu + ((u >> 16) & 1u)) >> 16;   // RNE
  return (short)(u16)r;
}

__device__ __forceinline__ void gload16(const void* g, void* l) {
  __builtin_amdgcn_global_load_lds(
      (const __attribute__((address_space(1))) u32*)g,
      (__attribute__((address_space(3))) u32*)l, 16, 0, 0);
}

// stage one 128-row half of a 256x64 bf16 tile (2 gload16/thread, 512 threads)
__device__ __forceinline__ void stage_half(const char* gop, long long ldb,
                                           long long rowbase, int tt, int h,
                                           u16* ldsop, int tid) {
#pragma unroll
  for (int l = 0; l < 2; ++l) {
    const int o   = (l * 512 + tid) * 16;
    const int rih = o >> 7;
    const int scb = (o & 127) ^ ((rih & 7) << 4);
    gload16(gop + (rowbase + h * 128 + rih) * ldb + (long long)tt * 128 + scb,
            (char*)ldsop + h * 16384 + o);
  }
}

#define SABUF(c) (SMEM + (c) * 16384)
#define SBBUF(c) (SMEM + 32768 + (c) * 16384)

#define RD_A(MH) do { _Pragma("unroll") for (int mi = 0; mi < 4; ++mi) { \
    const int row_ = wm * 64 + (MH) * 128 + mi * 16 + lr; \
    const int sw_ = (row_ & 7) << 4; const int rb_ = row_ << 7; \
    _Pragma("unroll") for (int kk = 0; kk < 2; ++kk) \
      af[mi][kk] = *(const s16x8*)(pa + rb_ + (((kk << 6) | (kg << 4)) ^ sw_)); } } while (0)

#define RD_B(NH) do { _Pragma("unroll") for (int nj = 0; nj < 2; ++nj) { \
    const int row_ = wn * 32 + (NH) * 128 + nj * 16 + lr; \
    const int sw_ = (row_ & 7) << 4; const int rb_ = row_ << 7; \
    _Pragma("unroll") for (int kk = 0; kk < 2; ++kk) \
      bf[NH][nj][kk] = *(const s16x8*)(pb + rb_ + (((kk << 6) | (kg << 4)) ^ sw_)); } } while (0)

#define MM(MH, NH) do { _Pragma("unroll") for (int kk = 0; kk < 2; ++kk) \
    _Pragma("unroll") for (int mi = 0; mi < 4; ++mi) \
    _Pragma("unroll") for (int nj = 0; nj < 2; ++nj) \
      acc[(MH) * 4 + mi][(NH) * 2 + nj] = __builtin_amdgcn_mfma_f32_16x16x32_bf16( \
        af[mi][kk], bf[NH][nj][kk], acc[(MH) * 4 + mi][(NH) * 2 + nj], 0, 0, 0); } while (0)

#define PH_SYNC do { __builtin_amdgcn_s_barrier(); \
    asm volatile("s_waitcnt lgkmcnt(0)"); \
    __builtin_amdgcn_sched_barrier(0); } while (0)

// Epilogue MODE: 1 = +bias0[col]; 2 = relu(+bias0[col]); 3 = exp(scale*acc) +
//   row-sum atomics into lsum; 4 = acc / lsum[z*M+row]; 5 = +bias, route
//   col>>10 to two [*,1024] outputs spaced 16777216 elems (fused QK, b0/b1);
//   6 = +bias0[row] (V^T projection: rows are embedding dims).
template<int MODE>
__device__ __forceinline__ void gemm_body(
    int tl, int gx,
    const u16* __restrict__ A, const u16* __restrict__ BT, u16* __restrict__ C,
    const float* __restrict__ bias0, const float* __restrict__ bias1,
    float* __restrict__ lsum,
    int M, int N, int K, float scale,
    long long sA, long long sB, long long sC, u16* SMEM) {
  const int tilesPerZ = (M >> 8) * gx;
  const int bz = tl / tilesPerZ;
  const int rem = tl - bz * tilesPerZ;
  const long long bm = (long long)(rem / gx) * 256;
  const long long bn = (long long)(rem % gx) * 256;

  const char* Ag = (const char*)(A + (long long)bz * sA);
  const char* Bg = (const char*)(BT + (long long)bz * sB);
  u16* Cb = C + (long long)bz * sC;
  const long long ldb = (long long)K * 2;

  const int tid = threadIdx.x;
  const int lane = tid & 63, wid = tid >> 6;
  const int lr = lane & 15, kg = lane >> 4;
  const int wm = wid >> 2, wn = wid & 3;
  const int NT = K >> 6;

  f32x4 acc[8][4] = {};
  s16x8 af[4][2];
  s16x8 bf[2][2][2];

  // prologue: T0 fully + T1 first halves; wait T0 (4 loads may stay in flight)
  stage_half(Ag, ldb, bm, 0, 0, SABUF(0), tid);
  stage_half(Bg, ldb, bn, 0, 0, SBBUF(0), tid);
  stage_half(Ag, ldb, bm, 0, 1, SABUF(0), tid);
  stage_half(Bg, ldb, bn, 0, 1, SBBUF(0), tid);
  stage_half(Ag, ldb, bm, 1, 0, SABUF(1), tid);
  stage_half(Bg, ldb, bn, 1, 0, SBBUF(1), tid);
  asm volatile("s_waitcnt vmcnt(4)");
  __builtin_amdgcn_s_barrier();

  for (int T = 0; T < NT; ++T) {
    const int c = T & 1, cn = c ^ 1;
    const char* pa = (const char*)SABUF(c);
    const char* pb = (const char*)SBBUF(c);

    // phase 0: (mh0,nh0); stage (T+1).Ah1
    RD_A(0); RD_B(0);
    if (T + 1 < NT) stage_half(Ag, ldb, bm, T + 1, 1, SABUF(cn), tid);
    PH_SYNC;
    __builtin_amdgcn_s_setprio(1); MM(0, 0); __builtin_amdgcn_s_setprio(0);
    __builtin_amdgcn_s_barrier();

    // phase 1: (mh0,nh1); stage (T+1).Bh1
    RD_B(1);
    if (T + 1 < NT) stage_half(Bg, ldb, bn, T + 1, 1, SBBUF(cn), tid);
    PH_SYNC;
    __builtin_amdgcn_s_setprio(1); MM(0, 1); __builtin_amdgcn_s_setprio(0);
    __builtin_amdgcn_s_barrier();

    // phase 2: (mh1,nh0); stage (T+2).Ah0
    RD_A(1);
    if (T + 2 < NT) stage_half(Ag, ldb, bm, T + 2, 0, SABUF(c), tid);
    PH_SYNC;
    __builtin_amdgcn_s_setprio(1); MM(1, 0); __builtin_amdgcn_s_setprio(0);
    __builtin_amdgcn_s_barrier();

    // phase 3: (mh1,nh1); stage (T+2).Bh0; counted boundary wait
    if (T + 2 < NT) stage_half(Bg, ldb, bn, T + 2, 0, SBBUF(c), tid);
    PH_SYNC;
    __builtin_amdgcn_s_setprio(1); MM(1, 1); __builtin_amdgcn_s_setprio(0);
    if (T + 2 < NT)      { asm volatile("s_waitcnt vmcnt(4)"); }
    else if (T + 1 < NT) { asm volatile("s_waitcnt vmcnt(0)"); }
    __builtin_amdgcn_s_barrier();
  }

  // epilogue: acc -> LDS (swizzled conflict-free) -> coalesced 16B stores
  const long long zM = (long long)bz * M;
  u16* obase; long long ldc, bnl;
  const float* bptr = bias0;
  if (MODE == 5) {
    const int sel = (int)(bn >> 10);
    obase = C + (long long)sel * 16777216;
    ldc = 1024; bnl = bn & 1023;
    bptr = (sel == 0 ? bias0 : bias1);
  } else { obase = Cb; ldc = N; bnl = bn; }

#pragma unroll
  for (int nh = 0; nh < 2; ++nh)
#pragma unroll
    for (int nj = 0; nj < 2; ++nj) {
      const int col = wn * 32 + nh * 128 + nj * 16 + lr;
      float bv = 0.f;
      if (MODE == 1 || MODE == 2 || MODE == 5) bv = bptr[bnl + col];
#pragma unroll
      for (int mh = 0; mh < 2; ++mh)
#pragma unroll
        for (int mi = 0; mi < 4; ++mi) {
          const int row0 = wm * 64 + mh * 128 + mi * 16 + kg * 4;
#pragma unroll
          for (int r = 0; r < 4; ++r) {
            float v = acc[mh * 4 + mi][nh * 2 + nj][r];
            if (MODE == 1 || MODE == 2 || MODE == 5) v = v * scale + bv;
            if (MODE == 2) v = fmaxf(v, 0.f);
            if (MODE == 3) v = __expf(v * scale);
            if (MODE == 4) v = v / lsum[zM + bm + row0 + r];
            if (MODE == 6) v = v * scale + bias0[bm + row0 + r];
            SMEM[(row0 + r) * 256 + (col ^ (kg << 4))] = (u16)f2bf(v);
          }
        }
    }
  __syncthreads();
#pragma unroll
  for (int i = 0; i < 16; ++i) {
    const int o   = (i * 512 + tid) * 16;
    const int row = o >> 9;
    const int wb  = o & 511;
    const int gs  = (wb >> 4) ^ (((row >> 2) & 3) << 1);
    s16x8 d = *(const s16x8*)((const char*)SMEM + row * 512 + (gs << 4));
    if (MODE == 3) {
      float s = 0.f;
#pragma unroll
      for (int j = 0; j < 8; ++j) s += bf2f(d[j]);
#pragma unroll
      for (int off = 1; off < 32; off <<= 1) s += __shfl_xor(s, off);
      if ((lane & 31) == 0) atomicAdd(&lsum[zM + bm + row], s);
    }
    *(s16x8*)((char*)obase + (((long long)bm + row) * ldc + bnl) * 2 + wb) = d;
  }
}

// standalone wrapper: grid encodes (gx, gy, z); bijective XCD swizzle (m204)
template<int MODE>
__global__ __launch_bounds__(512, 2)
void gemm256(const u16* __restrict__ A, const u16* __restrict__ BT,
             u16* __restrict__ C,
             const float* __restrict__ bias0, const float* __restrict__ bias1,
             float* __restrict__ lsum,
             int M, int N, int K, float scale,
             long long sA, long long sB, long long sC) {
  __shared__ u16 SMEM[65536];
  const int gx = gridDim.x, gy = gridDim.y;
  const int nwg = gx * gy * gridDim.z;
  const int orig = (blockIdx.z * gy + blockIdx.y) * gx + blockIdx.x;
  const int q = nwg >> 3, r8 = nwg & 7;
  const int xcd = orig & 7, pos = orig >> 3;
  const int wg = (xcd < r8 ? xcd * (q + 1) : r8 * (q + 1) + (xcd - r8) * q) + pos;
  gemm_body<MODE>(wg, gx, A, BT, C, bias0, bias1, lsum,
                  M, N, K, scale, sA, sB, sC, SMEM);
}

// merged QK + VT: 768 blocks, jointly XCD-swizzled; wg<512 -> QK, else VT
__global__ __launch_bounds__(512, 2)
void qkvt(const u16* __restrict__ XB, const u16* __restrict__ WQKT,
          u16* __restrict__ Q, const float* __restrict__ bq,
          const float* __restrict__ bk,
          const u16* __restrict__ WVT, u16* __restrict__ VT,
          const float* __restrict__ bv) {
  __shared__ u16 SMEM[65536];
  const int orig = blockIdx.x;            // nwg = 768, q = 96, r8 = 0
  const int wg = (orig & 7) * 96 + (orig >> 3);
  if (wg < 512) {
    // QK: [16384,1024] x [2048,1024]^T, MODE5 2-way col routing
    gemm_body<5>(wg, 8, XB, WQKT, Q, bq, bk, nullptr,
                 16384, 2048, 1024, 1.f, 0, 0, 0, SMEM);
  } else {
    // VT = Wv^T X^T per batch: A=WVT [1024,1024], BT=XB_z, C=VT_z [1024,2048]
    gemm_body<6>(wg - 512, 8, WVT, XB, VT, bv, nullptr, nullptr,
                 1024, 2048, 1024, 1.f, 0, 2048LL * 1024, 1024LL * 2048, SMEM);
  }
}

// ------------------------------------------- prep: cast x->bf16 + 6 weight transposes
__global__ __launch_bounds__(256) void prep(
    const float* __restrict__ x,  u16* __restrict__ XB,
    const float* __restrict__ Wq, const float* __restrict__ Wk,
    const float* __restrict__ Wv, const float* __restrict__ Wo,
    const float* __restrict__ W1, const float* __restrict__ W2,
    u16* __restrict__ WQT, u16* __restrict__ WKT, u16* __restrict__ WVT,
    u16* __restrict__ WOT, u16* __restrict__ W1T, u16* __restrict__ W2T) {
  __shared__ float tile[32][33];
  const int bid = blockIdx.x;
  const int t = threadIdx.x;
  if (bid < 16384) {
    const long long i = (long long)bid * 256 + t;
    f32x4 v = ((const f32x4*)x)[i];
    s16x4 o;
#pragma unroll
    for (int j = 0; j < 4; j++) o[j] = f2bf(v[j]);
    ((s16x4*)XB)[i] = o;
    return;
  }
  const float* in; u16* out; int R, C, tb;
  if (bid < 20480) {
    const int w = (bid - 16384) >> 10;
    tb = (bid - 16384) & 1023;
    in  = (w == 0 ? Wq : w == 1 ? Wk : w == 2 ? Wv : Wo);
    out = (w == 0 ? WQT : w == 1 ? WKT : w == 2 ? WVT : WOT);
    R = 1024; C = 1024;
  } else if (bid < 24576) {
    tb = bid - 20480; in = W1; out = W1T; R = 1024; C = 4096;
  } else {
    tb = bid - 24576; in = W2; out = W2T; R = 4096; C = 1024;
  }
  const int tpr = C >> 5;
  const int r0 = (tb / tpr) * 32, c0 = (tb % tpr) * 32;
  const int tx = t & 31, ty = t >> 5;
#pragma unroll
  for (int i = 0; i < 32; i += 8)
    tile[ty + i][tx] = in[(long long)(r0 + ty + i) * C + (c0 + tx)];
  __syncthreads();
#pragma unroll
  for (int i = 0; i < 32; i += 8)
    out[(long long)(c0 + ty + i) * R + (r0 + tx)] = (u16)f2bf(tile[tx][ty + i]);
}

// ------------------------------------------- LN(a_bf16 + b_bf16) -> bf16 or f32
template<bool OUTF32>
__global__ __launch_bounds__(256) void ln_add(const u16* __restrict__ a,
                                              const u16* __restrict__ b,
                                              const float* __restrict__ g,
                                              const float* __restrict__ be,
                                              void* __restrict__ outp) {
  const long long row = blockIdx.x;
  const int t = threadIdx.x;
  s16x4 avv = ((const s16x4*)(a + row * 1024))[t];
  s16x4 bvv = ((const s16x4*)(b + row * 1024))[t];
  float v[4]; float sum = 0.f, ss = 0.f;
#pragma unroll
  for (int j = 0; j < 4; j++) { v[j] = bf2f(avv[j]) + bf2f(bvv[j]); sum += v[j]; ss += v[j] * v[j]; }
#pragma unroll
  for (int off = 32; off > 0; off >>= 1) { sum += __shfl_xor(sum, off); ss += __shfl_xor(ss, off); }
  __shared__ float red[8];
  if ((t & 63) == 0) { red[t >> 6] = sum; red[4 + (t >> 6)] = ss; }
  __syncthreads();
  sum = (red[0] + red[1]) + (red[2] + red[3]);
  ss  = (red[4] + red[5]) + (red[6] + red[7]);
  const float mu   = sum * (1.f / 1024.f);
  const float var  = ss * (1.f / 1024.f) - mu * mu;
  const float rstd = rsqrtf(var + 1e-5f);
  if (OUTF32) {
    f32x4 o;
#pragma unroll
    for (int j = 0; j < 4; j++) {
      const int c = t * 4 + j;
      o[j] = (v[j] - mu) * rstd * g[c] + be[c];
    }
    ((f32x4*)((float*)outp + row * 1024))[t] = o;
  } else {
    s16x4 o;
#pragma unroll
    for (int j = 0; j < 4; j++) {
      const int c = t * 4 + j;
      o[j] = f2bf((v[j] - mu) * rstd * g[c] + be[c]);
    }
    *(s16x4*)&((u16*)outp)[row * 1024 + t * 4] = o;
  }
}

// ---------------------------------------------------------------- launcher
extern "C" void kernel_launch(void* const* d_in, const int* in_sizes, int n_in,
                              void* d_out, int out_size, void* d_ws, size_t ws_size,
                              hipStream_t stream) {
  const float* x   = (const float*)d_in[0];
  const float* Wq  = (const float*)d_in[1];
  const float* bq  = (const float*)d_in[2];
  const float* Wk  = (const float*)d_in[3];
  const float* bk  = (const float*)d_in[4];
  const float* Wv  = (const float*)d_in[5];
  const float* bv  = (const float*)d_in[6];
  const float* Wo  = (const float*)d_in[7];
  const float* bo  = (const float*)d_in[8];
  const float* g1  = (const float*)d_in[9];
  const float* b1  = (const float*)d_in[10];
  const float* g2  = (const float*)d_in[11];
  const float* b2  = (const float*)d_in[12];
  const float* W1  = (const float*)d_in[13];
  const float* bf1 = (const float*)d_in[14];
  const float* W2  = (const float*)d_in[15];
  const float* bf2 = (const float*)d_in[16];
  float* out = (float*)d_out;

  // ws layout (bytes), liveness-checked aliasing (same as R13):
  //  weights 0..25165824 (WQT/WKT contiguous for fused QK)
  //  XB 25165824 (32MiB) cast->LN1 | Q 58720256 | K 92274688 | V 125829120=lsum
  //  VT 159383552 | S 192937984 (64MiB): scores->PV, then AO2=S+0, H=S+32MiB,
  //  FFN=S+0. AO=Q after scores. HID=XB..V end (128MiB, dead by FFN1).
  char* ws = (char*)d_ws;
  u16* wsWQT = (u16*)(ws + 0);
  u16* wsWKT = (u16*)(ws + 2097152);
  u16* wsWVT = (u16*)(ws + 4194304);
  u16* wsWOT = (u16*)(ws + 6291456);
  u16* wsW1T = (u16*)(ws + 8388608);
  u16* wsW2T = (u16*)(ws + 16777216);
  u16* wsXB  = (u16*)(ws + 25165824);
  u16* wsQ   = (u16*)(ws + 58720256);
  u16* wsK   = (u16*)(ws + 92274688);
  u16* wsVT  = (u16*)(ws + 159383552);
  u16* wsS   = (u16*)(ws + 192937984);
  u16* wsAO  = wsQ;
  u16* wsAO2 = wsS;
  u16* wsH   = (u16*)(ws + 192937984 + 33554432);
  u16* wsHID = wsXB;
  u16* wsFFN = wsS;
  float* wsLSUM = (float*)(ws + 125829120);

  const float inv_sqrt_e = 0.03125f;   // 1/sqrt(1024)
  const float* nf = nullptr;
  float* nfm = nullptr;

  // 1) prep: cast x->bf16 + all weight transposes; zero lsum (independent)
  prep<<<28672, 256, 0, stream>>>(x, wsXB, Wq, Wk, Wv, Wo, W1, W2,
                                  wsWQT, wsWKT, wsWVT, wsWOT, wsW1T, wsW2T);
  hipMemsetAsync(wsLSUM, 0, 16384 * sizeof(float), stream);

  // 2) merged QK + VT (independent GEMMs, one 768-block dispatch)
  qkvt<<<768, 512, 0, stream>>>(wsXB, wsWQT, wsQ, bq, bk, wsWVT, wsVT, bv);

  // 3) P~ = exp(QK^T/32) + rowsum atomics into lsum
  gemm256<3><<<dim3(8, 8, 8), 512, 0, stream>>>(wsQ, wsK, wsS, nf, nf, wsLSUM,
                                                2048, 2048, 1024, inv_sqrt_e,
                                                2048LL * 1024, 2048LL * 1024, 2048LL * 2048);

  // 4) attn_out = (P~ V)/l -> AO (=Q region; Q dead after scores)
  gemm256<4><<<dim3(4, 8, 8), 512, 0, stream>>>(wsS, wsVT, wsAO, nf, nf, wsLSUM,
                                                2048, 1024, 2048, 1.f,
                                                2048LL * 2048, 1024LL * 2048, 2048LL * 1024);
  // 5) out-proj -> AO2 (=S region start; S dead after PV)
  gemm256<1><<<dim3(4, 64, 1), 512, 0, stream>>>(wsAO, wsWOT, wsAO2, bo, nf, nfm,
                                                 16384, 1024, 1024, 1.f, 0, 0, 0);

  // 6) h = LN(XB + AO2) -> H (S + 32MiB)
  ln_add<false><<<16384, 256, 0, stream>>>(wsXB, wsAO2, g1, b1, wsH);

  // 7) HID = relu(h W1 + bf1) -> HID (=XB..V, 128MiB, all dead by now)
  gemm256<2><<<dim3(16, 64, 1), 512, 0, stream>>>(wsH, wsW1T, wsHID, bf1, nf, nfm,
                                                  16384, 4096, 1024, 1.f, 0, 0, 0);

  // 8) FFN = HID W2 + bf2 -> FFN (=S start; AO2 dead after LN1)
  gemm256<1><<<dim3(4, 64, 1), 512, 0, stream>>>(wsHID, wsW2T, wsFFN, bf2, nf, nfm,
                                                 16384, 1024, 4096, 1.f, 0, 0, 0);

  // 9) out = LN(H + FFN), fp32
  ln_add<true><<<16384, 256, 0, stream>>>(wsH, wsFFN, g2, b2, out);

  (void)in_sizes; (void)n_in; (void)out_size; (void)ws_size;
}